// Round 1
// baseline (63.593 us; speedup 1.0000x reference)
//
#include <hip/hip_runtime.h>

// CurveGraphic2d: render 16 cubic Beziers onto 256x256 canvases.
// Output [16,256,256] float32. One fused kernel:
//   phase 1 (per block, redundant per pixel-tile): 32 curve samples -> LDS
//   phase 2: per-thread 4 pixels, min dist^2 over 32 samples, shade, float4 store.

constexpr int CH = 256, CW = 256;   // canvas
constexpr int S = 32;               // NUM_SAMPLES
constexpr int NB = 16;              // batch
constexpr int BLK = 256;            // threads/block
constexpr int PPT = 4;              // pixels/thread (consecutive in x)
constexpr float MAXLEN = 300.0f;
constexpr float EPS = 1e-6f;

__device__ inline float2 bez4(const float2 cp[4], float t) {
    float u = 1.0f - t;
    float b0 = u * u * u;
    float b1 = 3.0f * u * u * t;
    float b2 = 3.0f * u * t * t;
    float b3 = t * t * t;
    float2 r;
    r.x = b0 * cp[0].x + b1 * cp[1].x + b2 * cp[2].x + b3 * cp[3].x;
    r.y = b0 * cp[0].y + b1 * cp[1].y + b2 * cp[2].y + b3 * cp[3].y;
    return r;
}

__device__ inline float shade(float m, float wd, float aa) {
    float md = sqrtf(m);                 // min over d^2 == (min over d)^2
    float base = md / wd + EPS;
    float v = 1.0f - __expf(aa * __logf(base));   // base > 0 always
    return fminf(fmaxf(v, 0.0f), 1.0f);
}

__global__ __launch_bounds__(BLK) void curve_kernel(
    const float* __restrict__ inp,     // [16,4,2] normalized keypoints
    const float* __restrict__ widths,  // [16]
    const float* __restrict__ aas,     // [16]
    float* __restrict__ out)           // [16,256,256]
{
    const int b = blockIdx.y;
    const int tid = threadIdx.x;

    __shared__ float2 s_samp[S];
    __shared__ float2 s_cp[4];

    // ---- phase 1a: initial 32 samples from scaled control points ----
    float2 cp[4];
    if (tid < S) {
#pragma unroll
        for (int k = 0; k < 4; ++k) {
            cp[k].x = inp[(b * 4 + k) * 2 + 0] * 256.0f;  // y-coord (scaled by H)
            cp[k].y = inp[(b * 4 + k) * 2 + 1] * 256.0f;  // x-coord (scaled by W)
        }
        float t = (float)tid * (1.0f / 31.0f);
        s_samp[tid] = bez4(cp, t);
    }
    __syncthreads();

    // ---- phase 1b: arc length + de Casteljau left subdivision (thread 0) ----
    if (tid == 0) {
        float arc = 0.0f;
        for (int j = 0; j < S - 1; ++j) {
            float dy = s_samp[j + 1].x - s_samp[j].x;
            float dx = s_samp[j + 1].y - s_samp[j].y;
            arc += sqrtf(dy * dy + dx * dx);
        }
        float tt = fminf(1.0f, MAXLEN / (arc + EPS));
        float u = 1.0f - tt;
        float2 a01, a12, a23, q0, q1, c0;
        a01.x = u * cp[0].x + tt * cp[1].x;  a01.y = u * cp[0].y + tt * cp[1].y;
        a12.x = u * cp[1].x + tt * cp[2].x;  a12.y = u * cp[1].y + tt * cp[2].y;
        a23.x = u * cp[2].x + tt * cp[3].x;  a23.y = u * cp[2].y + tt * cp[3].y;
        q0.x = u * a01.x + tt * a12.x;       q0.y = u * a01.y + tt * a12.y;
        q1.x = u * a12.x + tt * a23.x;       q1.y = u * a12.y + tt * a23.y;
        c0.x = u * q0.x + tt * q1.x;         c0.y = u * q0.y + tt * q1.y;
        s_cp[0] = cp[0]; s_cp[1] = a01; s_cp[2] = q0; s_cp[3] = c0;
    }
    __syncthreads();

    // ---- phase 1c: final 32 samples from truncated control points ----
    if (tid < S) {
        float2 cpl[4] = { s_cp[0], s_cp[1], s_cp[2], s_cp[3] };
        float t = (float)tid * (1.0f / 31.0f);
        s_samp[tid] = bez4(cpl, t);
    }
    __syncthreads();

    // ---- phase 2: 4 consecutive pixels per thread ----
    const float wd = widths[b];
    const float aa = aas[b];
    const int p0 = blockIdx.x * (BLK * PPT) + tid * PPT;  // flat pixel index, 4-aligned
    const float fy = (float)(p0 >> 8);      // row (W=256)
    const float fx = (float)(p0 & 255);     // col of first pixel

    float m0 = 1e30f, m1 = 1e30f, m2 = 1e30f, m3 = 1e30f;
#pragma unroll
    for (int j = 0; j < S; ++j) {
        float2 sp = s_samp[j];              // wave-uniform LDS read (broadcast)
        float dy = fy - sp.x;
        float dy2 = dy * dy;
        float dx0 = fx - sp.y;
        float dx1 = fx + 1.0f - sp.y;
        float dx2 = fx + 2.0f - sp.y;
        float dx3 = fx + 3.0f - sp.y;
        m0 = fminf(m0, fmaf(dx0, dx0, dy2));
        m1 = fminf(m1, fmaf(dx1, dx1, dy2));
        m2 = fminf(m2, fmaf(dx2, dx2, dy2));
        m3 = fminf(m3, fmaf(dx3, dx3, dy2));
    }

    float4 o;
    o.x = shade(m0, wd, aa);
    o.y = shade(m1, wd, aa);
    o.z = shade(m2, wd, aa);
    o.w = shade(m3, wd, aa);
    *reinterpret_cast<float4*>(out + b * (CH * CW) + p0) = o;
}

extern "C" void kernel_launch(void* const* d_in, const int* in_sizes, int n_in,
                              void* d_out, int out_size, void* d_ws, size_t ws_size,
                              hipStream_t stream) {
    const float* inp = (const float*)d_in[0];     // [16,4,2]
    const float* widths = (const float*)d_in[1];  // [16]
    const float* aas = (const float*)d_in[2];     // [16]
    float* out = (float*)d_out;                   // [16,256,256]

    dim3 grid((CH * CW) / (BLK * PPT), NB);       // (64, 16)
    curve_kernel<<<grid, BLK, 0, stream>>>(inp, widths, aas, out);
}

// Round 2
// 63.190 us; speedup vs baseline: 1.0064x; 1.0064x over previous
//
#include <hip/hip_runtime.h>

// CurveGraphic2d: render 16 cubic Beziers onto 256x256 canvases.
// Output [16,256,256] float32.
// v2: 32x32 pixel tiles (grid 8x8x16). Per tile: rebuild the curve's 32
// samples in LDS (cheap, redundant), then a conservative rect-distance prune:
// if every sample is >= width away from the tile rect, the whole tile is
// exactly 0 (clip(1 - (d/w+eps)^aa) <= 0) -> store zeros, skip the
// 32-sample min-distance loop and the transcendental epilogue.

constexpr int CH = 256, CW = 256;   // canvas
constexpr int S = 32;               // NUM_SAMPLES
constexpr int NB = 16;              // batch
constexpr int BLK = 256;            // threads/block
constexpr int TILE = 32;            // tile is 32x32 px, 4 px/thread in x
constexpr float MAXLEN = 300.0f;
constexpr float EPS = 1e-6f;

__device__ inline float2 bez4(const float2 cp[4], float t) {
    float u = 1.0f - t;
    float b0 = u * u * u;
    float b1 = 3.0f * u * u * t;
    float b2 = 3.0f * u * t * t;
    float b3 = t * t * t;
    float2 r;
    r.x = b0 * cp[0].x + b1 * cp[1].x + b2 * cp[2].x + b3 * cp[3].x;
    r.y = b0 * cp[0].y + b1 * cp[1].y + b2 * cp[2].y + b3 * cp[3].y;
    return r;
}

__device__ inline float shade(float m, float wd, float aa) {
    float md = sqrtf(m);                 // min over d^2 == (min over d)^2
    float base = md / wd + EPS;
    float v = 1.0f - __expf(aa * __logf(base));   // base > 0 always
    return fminf(fmaxf(v, 0.0f), 1.0f);
}

__global__ __launch_bounds__(BLK) void curve_kernel(
    const float* __restrict__ inp,     // [16,4,2] normalized keypoints
    const float* __restrict__ widths,  // [16]
    const float* __restrict__ aas,     // [16]
    float* __restrict__ out)           // [16,256,256]
{
    const int b = blockIdx.z;
    const int tx0 = blockIdx.x * TILE;   // tile col origin
    const int ty0 = blockIdx.y * TILE;   // tile row origin
    const int tid = threadIdx.x;

    __shared__ float2 s_samp[S];
    __shared__ float2 s_cp[4];
    __shared__ int s_active;

    // ---- phase 1a: initial 32 samples from scaled control points ----
    float2 cp[4];
    if (tid < S) {
#pragma unroll
        for (int k = 0; k < 4; ++k) {
            cp[k].x = inp[(b * 4 + k) * 2 + 0] * 256.0f;  // y (scaled by H)
            cp[k].y = inp[(b * 4 + k) * 2 + 1] * 256.0f;  // x (scaled by W)
        }
        float t = (float)tid * (1.0f / 31.0f);
        s_samp[tid] = bez4(cp, t);
    }
    __syncthreads();

    // ---- phase 1b: arc length + de Casteljau left subdivision (thread 0) ----
    if (tid == 0) {
        float arc = 0.0f;
        for (int j = 0; j < S - 1; ++j) {
            float dy = s_samp[j + 1].x - s_samp[j].x;
            float dx = s_samp[j + 1].y - s_samp[j].y;
            arc += sqrtf(dy * dy + dx * dx);
        }
        float tt = fminf(1.0f, MAXLEN / (arc + EPS));
        float u = 1.0f - tt;
        float2 a01, a12, a23, q0, q1, c0;
        a01.x = u * cp[0].x + tt * cp[1].x;  a01.y = u * cp[0].y + tt * cp[1].y;
        a12.x = u * cp[1].x + tt * cp[2].x;  a12.y = u * cp[1].y + tt * cp[2].y;
        a23.x = u * cp[2].x + tt * cp[3].x;  a23.y = u * cp[2].y + tt * cp[3].y;
        q0.x = u * a01.x + tt * a12.x;       q0.y = u * a01.y + tt * a12.y;
        q1.x = u * a12.x + tt * a23.x;       q1.y = u * a12.y + tt * a23.y;
        c0.x = u * q0.x + tt * q1.x;         c0.y = u * q0.y + tt * q1.y;
        s_cp[0] = cp[0]; s_cp[1] = a01; s_cp[2] = q0; s_cp[3] = c0;
    }
    __syncthreads();

    // ---- phase 1c: final 32 samples from truncated control points ----
    if (tid < S) {
        float2 cpl[4] = { s_cp[0], s_cp[1], s_cp[2], s_cp[3] };
        float t = (float)tid * (1.0f / 31.0f);
        s_samp[tid] = bez4(cpl, t);
    }
    __syncthreads();

    // ---- tile prune: exact-zero test (min_d >= w  ->  pixel value 0) ----
    const float wd = widths[b];
    bool pred = false;
    if (tid < S) {
        float2 sp = s_samp[tid];
        // continuous rect-distance lower bound (sp.x = y-coord, sp.y = x-coord)
        float dyl = fmaxf(0.0f, fmaxf((float)ty0 - sp.x, sp.x - (float)(ty0 + TILE - 1)));
        float dxl = fmaxf(0.0f, fmaxf((float)tx0 - sp.y, sp.y - (float)(tx0 + TILE - 1)));
        pred = fmaf(dxl, dxl, dyl * dyl) < wd * wd;
    }
    unsigned long long mask = __ballot(pred);   // wave 0 holds tids 0..63
    if (tid == 0) s_active = (mask != 0ULL);
    __syncthreads();

    // thread -> pixel mapping: 4 consecutive px in x; 8 col-groups x 32 rows
    const int row = ty0 + (tid >> 3);
    const int col = tx0 + (tid & 7) * 4;
    float* dst = out + b * (CH * CW) + row * CW + col;

    if (!s_active) {
        float4 z = make_float4(0.0f, 0.0f, 0.0f, 0.0f);
        *reinterpret_cast<float4*>(dst) = z;
        return;
    }

    // ---- active tile: min over 32 samples of squared distance ----
    const float aa = aas[b];
    const float fy = (float)row;
    const float fx = (float)col;

    float m0 = 1e30f, m1 = 1e30f, m2 = 1e30f, m3 = 1e30f;
#pragma unroll
    for (int j = 0; j < S; ++j) {
        float2 sp = s_samp[j];              // wave-uniform LDS read (broadcast)
        float dy = fy - sp.x;
        float dy2 = dy * dy;
        float dx0 = fx - sp.y;
        float dx1 = fx + 1.0f - sp.y;
        float dx2 = fx + 2.0f - sp.y;
        float dx3 = fx + 3.0f - sp.y;
        m0 = fminf(m0, fmaf(dx0, dx0, dy2));
        m1 = fminf(m1, fmaf(dx1, dx1, dy2));
        m2 = fminf(m2, fmaf(dx2, dx2, dy2));
        m3 = fminf(m3, fmaf(dx3, dx3, dy2));
    }

    float4 o;
    o.x = shade(m0, wd, aa);
    o.y = shade(m1, wd, aa);
    o.z = shade(m2, wd, aa);
    o.w = shade(m3, wd, aa);
    *reinterpret_cast<float4*>(dst) = o;
}

extern "C" void kernel_launch(void* const* d_in, const int* in_sizes, int n_in,
                              void* d_out, int out_size, void* d_ws, size_t ws_size,
                              hipStream_t stream) {
    const float* inp = (const float*)d_in[0];     // [16,4,2]
    const float* widths = (const float*)d_in[1];  // [16]
    const float* aas = (const float*)d_in[2];     // [16]
    float* out = (float*)d_out;                   // [16,256,256]

    dim3 grid(CW / TILE, CH / TILE, NB);          // (8, 8, 16)
    curve_kernel<<<grid, BLK, 0, stream>>>(inp, widths, aas, out);
}